// Round 5
// baseline (106.547 us; speedup 1.0000x reference)
//
#include <hip/hip_runtime.h>

// MeanAggregator: out[b, :] = mean_{s<10} features[idx[b,s], :]
// features: float32 [1'000'000, 128]; idx: int32 [100'000, 10]; out: float32 [100'000, 128]
//
// R5: node-ID-phased gather WITHOUT cooperative launch (R4's coop launch
// silently failed). Two plain kernels serialized on the stream:
//   phase 0: acc = sum of neighbors with id <  half; store RAW sums to out
//   phase 1: acc = load(out) + sum of neighbors with id >= half; store acc/10
// Each phase's feature working set (~316k unique rows ~= 162 MB) fits the
// 256 MB L3, so within-phase duplicate indices hit cache instead of re-
// fetching HBM (the ~188 MB the flat kernel wasted). The 51 MB partial
// round-trip rides in L3 (written at end of phase 0, read early in phase 1).
// Deterministic across replays: phase 0 overwrites out unconditionally.

#define FEAT_DIM   128
#define NUM_SAMPLE 10
#define QUADS      (FEAT_DIM / 4)       // 32 lanes per row
#define ROWS_PER_BLOCK (256 / QUADS)    // 8

typedef float floatx4 __attribute__((ext_vector_type(4)));

template <int PHASE>
__global__ __launch_bounds__(256) void mean_agg_phase(
    const float* __restrict__ feats,
    const int*   __restrict__ idx,
    float*       __restrict__ out,
    int batch, int half)
{
    const int row  = blockIdx.x * ROWS_PER_BLOCK + (threadIdx.x >> 5);
    const int quad = threadIdx.x & (QUADS - 1);
    if (row >= batch) return;

    const int* __restrict__ rid = idx + (long long)row * NUM_SAMPLE;
    int nid[NUM_SAMPLE];
#pragma unroll
    for (int s = 0; s < NUM_SAMPLE; ++s) nid[s] = rid[s];

    floatx4* outp = reinterpret_cast<floatx4*>(out + (long long)row * FEAT_DIM) + quad;

    floatx4 acc;
    if (PHASE == 0) acc = (floatx4)0.0f;
    else            acc = *outp;          // partial sums from phase 0 (L3-hot)

#pragma unroll
    for (int s = 0; s < NUM_SAMPLE; ++s) {
        const int id = nid[s];
        const bool mine = (PHASE == 0) ? (id < half) : (id >= half);
        if (mine) {
            const floatx4* __restrict__ src =
                reinterpret_cast<const floatx4*>(feats + (long long)id * FEAT_DIM) + quad;
            acc += *src;
        }
    }

    if (PHASE == 0) {
        *outp = acc;                      // raw partial; keep in L3 for phase 1
    } else {
        acc *= (1.0f / (float)NUM_SAMPLE);
        __builtin_nontemporal_store(acc, outp);   // final, streamed once
    }
}

extern "C" void kernel_launch(void* const* d_in, const int* in_sizes, int n_in,
                              void* d_out, int out_size, void* d_ws, size_t ws_size,
                              hipStream_t stream)
{
    const float* feats = (const float*)d_in[0];   // [N_NODES * FEAT_DIM]
    const int*   idx   = (const int*)d_in[1];     // [BATCH * NUM_SAMPLE]
    float*       out   = (float*)d_out;           // [BATCH * FEAT_DIM]

    const int batch   = in_sizes[1] / NUM_SAMPLE; // 100'000
    const int n_nodes = in_sizes[0] / FEAT_DIM;   // 1'000'000
    const int half    = (n_nodes + 1) / 2;

    dim3 block(256);
    dim3 grid((batch + ROWS_PER_BLOCK - 1) / ROWS_PER_BLOCK);
    mean_agg_phase<0><<<grid, block, 0, stream>>>(feats, idx, out, batch, half);
    mean_agg_phase<1><<<grid, block, 0, stream>>>(feats, idx, out, batch, half);
}

// Round 6
// 85.811 us; speedup vs baseline: 1.2417x; 1.2417x over previous
//
#include <hip/hip_runtime.h>

// MeanAggregator: out[b, :] = mean_{s<10} features[idx[b,s], :]
// features: float32 [1'000'000, 128]; idx: int32 [100'000, 10]; out: float32 [100'000, 128]
//
// FINAL (revert to R3 flat kernel — best measured: 86.2 us):
// 32 lanes per row, each lane owns one float4 of the 128-dim feature.
// 256-thread block -> 8 rows/block. Each (row, neighbor) gather is a 512 B
// contiguous, fully-coalesced transaction; 10 loads in flight per lane.
// Traffic is compulsory: 512 MB gather + 4 MB idx + 51 MB write = 567 MB
// at ~6.6 TB/s = the fill-kernel-measured machine ceiling.
// Phased-L3-dedupe (R5) regressed to 106 us: partial round-trip + halved MLP
// outweigh dedupe; L3 shows ~zero dedupe on this random stream regardless.

#define FEAT_DIM   128
#define NUM_SAMPLE 10
#define QUADS      (FEAT_DIM / 4)       // 32 lanes per row
#define ROWS_PER_BLOCK (256 / QUADS)    // 8

typedef float floatx4 __attribute__((ext_vector_type(4)));

__global__ __launch_bounds__(256) void MeanAggregator_13846974562846_kernel(
    const float* __restrict__ feats,
    const int*   __restrict__ idx,
    float*       __restrict__ out,
    int batch)
{
    const int row  = blockIdx.x * ROWS_PER_BLOCK + (threadIdx.x >> 5);
    const int quad = threadIdx.x & (QUADS - 1);
    if (row >= batch) return;

    // Hoist the 10 neighbor indices into registers (uniform address across the
    // 32-lane group -> broadcast; keeps all 10 gather loads in flight below).
    const int* __restrict__ rid = idx + (long long)row * NUM_SAMPLE;
    int nid[NUM_SAMPLE];
#pragma unroll
    for (int s = 0; s < NUM_SAMPLE; ++s) nid[s] = rid[s];

    floatx4 acc = (floatx4)0.0f;
#pragma unroll
    for (int s = 0; s < NUM_SAMPLE; ++s) {
        const floatx4* __restrict__ src =
            reinterpret_cast<const floatx4*>(feats + (long long)nid[s] * FEAT_DIM) + quad;
        acc += *src;
    }

    acc *= (1.0f / (float)NUM_SAMPLE);

    floatx4* dst = reinterpret_cast<floatx4*>(out + (long long)row * FEAT_DIM) + quad;
    __builtin_nontemporal_store(acc, dst);
}

extern "C" void kernel_launch(void* const* d_in, const int* in_sizes, int n_in,
                              void* d_out, int out_size, void* d_ws, size_t ws_size,
                              hipStream_t stream)
{
    const float* feats = (const float*)d_in[0];   // [N_NODES * FEAT_DIM]
    const int*   idx   = (const int*)d_in[1];     // [BATCH * NUM_SAMPLE]
    float*       out   = (float*)d_out;           // [BATCH * FEAT_DIM]

    const int batch = in_sizes[1] / NUM_SAMPLE;   // 100'000

    dim3 block(256);
    dim3 grid((batch + ROWS_PER_BLOCK - 1) / ROWS_PER_BLOCK);
    MeanAggregator_13846974562846_kernel<<<grid, block, 0, stream>>>(feats, idx, out, batch);
}